// Round 9
// baseline (671.925 us; speedup 1.0000x reference)
//
#include <hip/hip_runtime.h>
#include <hip/hip_fp16.h>
#include <math.h>

// ---------------------------------------------------------------------------
// GAT encoder, 2 layers.
//   GEMMs: single-term fp16 MFMA (mfma_f32_16x16x32_f16, fp32 accum),
//          single LDS buffer + register prefetch (round-5 structure; dbuf,
//          gemm+scatter fusion, and nid-stream variants all regressed).
//   CSR: padded to even degree. Edge record is ONE packed u32 (src<<16|dst,
//          N<65536): scatter does a single 4B random store (half of int2's
//          partial-line write amplification), no random reads (fill seeded
//          = row_start in scan_add). Sentinels (0xFFFFFFFF) are written only
//          into the <=1 hole per odd-degree row + tail pad slots by scan_add
//          (no 13.6MB sentinel memset).
//   fill_rec (2 edges/thread) reads packed edges sequentially, computes
//          w = exp(leaky(a_s[src]+a_d[dst])) per head; rec[i] =
//          {src, w0|w1, w2|w3, 0} (fp16). Sentinel -> zero record.
//   Aggregation: 1 node/wave, 2 edges/iteration (lanes 0-31 edge p, lanes
//          32-63 edge p+1; 16B/lane -> one 1KB gather per pair), depth-4
//          rotation-free software pipeline, prefetch distance 8 edges.
//          Pinned at the L2-miss/Infinity-Cache random-service floor
//          (~3.8 TB/s eff, FETCH ~199MB) - identical counters for 9 rounds.
// ---------------------------------------------------------------------------

#define LEAKY_SLOPE 0.2f

typedef __attribute__((ext_vector_type(8))) short short8v;      // 16B
typedef __attribute__((ext_vector_type(8))) _Float16 half8v;    // 8 fp16
typedef __attribute__((ext_vector_type(4))) float float4v;

// ---------------- fused prep: W->fp16 transposed + x->fp16 + histogram -----

__global__ void prep_kernel(const float* __restrict__ W1, __half* __restrict__ Bt1,
                            const float* __restrict__ W2, __half* __restrict__ Bt2,
                            const float* __restrict__ x, __half* __restrict__ x_h,
                            const int* __restrict__ ei, int* __restrict__ cnt,
                            int E, int N, int xblocks) {
    int b = blockIdx.x;
    if (b < 128) {                       // W1: [128][256] -> Bt1[c*128+k]
        int idx = b * 256 + threadIdx.x;
        int k = idx >> 8, c = idx & 255;
        Bt1[c * 128 + k] = __float2half(W1[idx]);
    } else if (b < 384) {                // W2: [256][256] -> Bt2[c*256+k]
        int idx = (b - 128) * 256 + threadIdx.x;
        int k = idx >> 8, c = idx & 255;
        Bt2[c * 256 + k] = __float2half(W2[idx]);
    } else if (b < 384 + xblocks) {      // x -> fp16, 4 elems/thread
        int t = (b - 384) * 256 + threadIdx.x;
        if (t < N * 32) {
            float4 v = *(const float4*)&x[(size_t)t * 4];
            __half2 h01 = __floats2half2_rn(v.x, v.y);
            __half2 h23 = __floats2half2_rn(v.z, v.w);
            uint2 pk = {*(unsigned*)&h01, *(unsigned*)&h23};
            *(uint2*)&x_h[(size_t)t * 4] = pk;
        }
    } else {                             // degree histogram (incl. self-loops)
        int e = (b - 384 - xblocks) * 256 + threadIdx.x;
        if (e < E + N) {
            int dst = (e < E) ? ei[E + e] : (e - E);
            atomicAdd(&cnt[dst], 1);
        }
    }
}

// ---------------- CSR build (padded to even degree) ----------------

__global__ __launch_bounds__(1024) void scan_block(const int* __restrict__ cnt,
                                                   int* __restrict__ row_start,
                                                   int* __restrict__ partials,
                                                   int n) {
    __shared__ int wsum[16];
    int tid = threadIdx.x, lane = tid & 63, wid = tid >> 6;
    int gi = blockIdx.x * 1024 + tid;
    int v = (gi < n) ? ((cnt[gi] + 1) & ~1) : 0;   // pad degree to even
    int x = v;
#pragma unroll
    for (int off = 1; off < 64; off <<= 1) {
        int y = __shfl_up(x, off, 64);
        if (lane >= off) x += y;
    }
    if (lane == 63) wsum[wid] = x;
    __syncthreads();
    if (wid == 0 && lane < 16) {
        int w = wsum[lane];
#pragma unroll
        for (int off = 1; off < 16; off <<= 1) {
            int y = __shfl_up(w, off, 16);
            if (lane >= off) w += y;
        }
        wsum[lane] = w;
    }
    __syncthreads();
    int excl = x - v + ((wid > 0) ? wsum[wid - 1] : 0);
    if (gi < n) row_start[gi] = excl;
    if (tid == 1023) partials[blockIdx.x] = wsum[15];
}

// scan_add: partials-scan folded in; seeds fill[] = row_start; writes the
// 0xFFFFFFFF sentinel into the <=1 hole of each odd-degree row; thread 0
// sentinels the tail pad slots.
__global__ __launch_bounds__(1024) void scan_add(int* __restrict__ row_start,
                                                 const int* __restrict__ partials,
                                                 const int* __restrict__ cnt,
                                                 int* __restrict__ fill,
                                                 unsigned* __restrict__ edge_pk,
                                                 int n, int nb, int etotmax) {
    __shared__ int spart[2];             // [excl prefix for this block, total]
    if (threadIdx.x < 64) {
        int lane = threadIdx.x;
        int v = (lane < nb) ? partials[lane] : 0;
        int x = v;
#pragma unroll
        for (int off = 1; off < 64; off <<= 1) {
            int y = __shfl_up(x, off, 64);
            if (lane >= off) x += y;
        }
        if (lane == (int)blockIdx.x) spart[0] = x - v;   // exclusive prefix
        if (lane == nb - 1) spart[1] = x;                // grand total
    }
    __syncthreads();
    int gi = blockIdx.x * 1024 + threadIdx.x;
    if (gi < n) {
        int v = row_start[gi] + spart[0];
        row_start[gi] = v;
        fill[gi] = v;                    // scatter cursor starts at row base
        int d = cnt[gi];
        if (d & 1) edge_pk[v + d] = 0xFFFFFFFFu;   // the single hole slot
    }
    if (gi == 0) {
        int total = spart[1];
        row_start[n] = total;
        for (int j = total; j < etotmax; j++) edge_pk[j] = 0xFFFFFFFFu;
    }
}

__global__ void scatter_kernel(const int* __restrict__ ei,
                               int* __restrict__ fill,
                               unsigned* __restrict__ edge_pk, int E, int Etot) {
    int e = blockIdx.x * blockDim.x + threadIdx.x;
    if (e >= Etot) return;
    int src, dst;
    if (e < E) { src = ei[e]; dst = ei[E + e]; }
    else       { src = e - E; dst = e - E; }
    int pos = atomicAdd(&fill[dst], 1);              // seeded = row_start
    edge_pk[pos] = ((unsigned)src << 16) | (unsigned)dst;  // one 4B store
}

// rec[i] = {src, w0|w1, w2|w3, pad}, w = exp(leaky(a_s+a_d)) fp16.
// Sentinel (0xFFFFFFFF) -> zero record. 2 edges per thread.
__device__ __forceinline__ uint4 make_rec(unsigned pk,
                                          const __half* __restrict__ a_s_h,
                                          const float* __restrict__ a_d) {
    if (pk == 0xFFFFFFFFu) {
        uint4 z = {0u, 0u, 0u, 0u};
        return z;
    }
    unsigned src = pk >> 16, dst = pk & 0xFFFFu;
    uint2 as2 = *(const uint2*)&a_s_h[(size_t)src * 4];
    float4 ad4 = *(const float4*)&a_d[(size_t)dst * 4];
    float2 f01 = __half22float2(*(const __half2*)&as2.x);
    float2 f23 = __half22float2(*(const __half2*)&as2.y);
    float e0 = f01.x + ad4.x, e1 = f01.y + ad4.y;
    float e2 = f23.x + ad4.z, e3 = f23.y + ad4.w;
    e0 = (e0 > 0.f) ? e0 : LEAKY_SLOPE * e0;
    e1 = (e1 > 0.f) ? e1 : LEAKY_SLOPE * e1;
    e2 = (e2 > 0.f) ? e2 : LEAKY_SLOPE * e2;
    e3 = (e3 > 0.f) ? e3 : LEAKY_SLOPE * e3;
    __half2 w01 = __floats2half2_rn(__expf(e0), __expf(e1));
    __half2 w23 = __floats2half2_rn(__expf(e2), __expf(e3));
    uint4 r = {src, *(unsigned*)&w01, *(unsigned*)&w23, 0u};
    return r;
}

__global__ void fill_rec(const uint2* __restrict__ edge_pk2,
                         const __half* __restrict__ a_s_h,
                         const float* __restrict__ a_d,
                         uint4* __restrict__ rec, int npairs) {
    int i = blockIdx.x * blockDim.x + threadIdx.x;
    if (i >= npairs) return;
    uint2 pp = edge_pk2[i];              // {pk0, pk1}
    uint4 r0 = make_rec(pp.x, a_s_h, a_d);
    uint4 r1 = make_rec(pp.y, a_s_h, a_d);
    rec[2 * i] = r0;
    rec[2 * i + 1] = r1;
}

// ---------------- fp16 MFMA GEMM + fused attention dots ---------------
// C[M,256] = A[M,K] @ B[K,256], C stored fp16. A fp16, B fp16 transposed.
// 128x128 tile, BK=32, 2x2 waves, 16 mfma per K-step, register prefetch.

template <int K>
__global__ __launch_bounds__(256) void gemm_mfma(
    const __half* __restrict__ Ah, const __half* __restrict__ Bt,
    __half* __restrict__ Ch,
    const float* __restrict__ att_src, const float* __restrict__ att_dst,
    __half* __restrict__ a_s_out, float* __restrict__ a_d_out, int M) {
    __shared__ short As[128][40];   // [m][k], pad 32->40
    __shared__ short Bs[128][40];   // [n][k] (transposed)

    const int col0 = (blockIdx.x & 1) * 128;
    const int row0 = (blockIdx.x >> 1) * 128;
    const int tid = threadIdx.x;
    const int lane = tid & 63;
    const int wave = tid >> 6;
    const int wr = wave >> 1, wc = wave & 1;
    const int quad = lane >> 4, lc = lane & 15;

    float4v acc[4][4] = {};

    const short* Abits = (const short*)Ah;
    const short* Bbits = (const short*)Bt;

    // staging geometry: thread covers rows (tid>>2) and (tid>>2)+64,
    // k-chunk (tid&3)*8, for both A and B.
    const int sr = tid >> 2;
    const int ko = (tid & 3) * 8;
    const int ga0 = row0 + sr, ga1 = ga0 + 64;
    const size_t gb0 = (size_t)(col0 + sr) * K + ko;
    const size_t gb1 = (size_t)(col0 + sr + 64) * K + ko;

    short8v pa0, pa1, pb0, pb1;
#define LOADT(k0)                                                          \
    {                                                                      \
        pa0 = {}; pa1 = {};                                                \
        if (ga0 < M) pa0 = *(const short8v*)&Abits[(size_t)ga0 * K + (k0) + ko]; \
        if (ga1 < M) pa1 = *(const short8v*)&Abits[(size_t)ga1 * K + (k0) + ko]; \
        pb0 = *(const short8v*)&Bbits[gb0 + (k0)];                         \
        pb1 = *(const short8v*)&Bbits[gb1 + (k0)];                         \
    }

    LOADT(0);

#pragma unroll
    for (int k0 = 0; k0 < K; k0 += 32) {
        *(short8v*)&As[sr][ko] = pa0;
        *(short8v*)&As[sr + 64][ko] = pa1;
        *(short8v*)&Bs[sr][ko] = pb0;
        *(short8v*)&Bs[sr + 64][ko] = pb1;
        __syncthreads();

        if (k0 + 32 < K) LOADT(k0 + 32);   // prefetch under MFMA

        half8v a[4], bv[4];
#pragma unroll
        for (int mt = 0; mt < 4; mt++) {
            int r = wr * 64 + mt * 16 + lc;
            a[mt] = *(const half8v*)&As[r][quad * 8];
        }
#pragma unroll
        for (int nt = 0; nt < 4; nt++) {
            int n = wc * 64 + nt * 16 + lc;
            bv[nt] = *(const half8v*)&Bs[n][quad * 8];
        }
#pragma unroll
        for (int mt = 0; mt < 4; mt++)
#pragma unroll
            for (int nt = 0; nt < 4; nt++)
                acc[mt][nt] = __builtin_amdgcn_mfma_f32_16x16x32_f16(
                    a[mt], bv[nt], acc[mt][nt], 0, 0, 0);
        __syncthreads();
    }
#undef LOADT

    // ---- epilogue: wave's 64 cols = head; C/D: col=lc(+nt*16), row=quad*4+r
    const int head = (col0 >> 6) + wc;
    float as_c[4], ad_c[4];
#pragma unroll
    for (int nt = 0; nt < 4; nt++) {
        as_c[nt] = att_src[head * 64 + nt * 16 + lc];
        ad_c[nt] = att_dst[head * 64 + nt * 16 + lc];
    }

#pragma unroll
    for (int mt = 0; mt < 4; mt++) {
#pragma unroll
        for (int r = 0; r < 4; r++) {
            int gr = row0 + wr * 64 + mt * 16 + quad * 4 + r;
            float ps = 0.f, pd = 0.f;
#pragma unroll
            for (int nt = 0; nt < 4; nt++) {
                float c = acc[mt][nt][r];
                ps = fmaf(c, as_c[nt], ps);
                pd = fmaf(c, ad_c[nt], pd);
                if (gr < M)
                    Ch[(size_t)gr * 256 + col0 + wc * 64 + nt * 16 + lc] =
                        __float2half(c);
            }
#pragma unroll
            for (int off = 1; off < 16; off <<= 1) {
                ps += __shfl_xor(ps, off, 64);
                pd += __shfl_xor(pd, off, 64);
            }
            if (lc == 0 && gr < M) {
                a_s_out[gr * 4 + head] = __float2half(ps);
                a_d_out[gr * 4 + head] = pd;
            }
        }
    }
}

// ---------------- fused aggregate + bias + elu ----------------
// 1 node/wave, 2 edges/iteration, padded-even rows: no clamps, no tail
// checks. Depth-4 rotation-free pipeline, prefetch distance 8 edges.

template <bool OUT_HALF>
__global__ __launch_bounds__(256) void gat_aggregate(
    const __half* __restrict__ hh, const uint4* __restrict__ rec,
    const int* __restrict__ row_start, const float* __restrict__ bias,
    void* __restrict__ outp, int n) {
    int node = (blockIdx.x * blockDim.x + threadIdx.x) >> 6;
    if (node >= n) return;                 // wave-uniform
    int lane = threadIdx.x & 63;
    int half = lane >> 5, l32 = lane & 31;
    int head = l32 >> 3;
    unsigned wsh = (head & 1) << 4;        // 16-bit select shift, hoisted

    int beg = row_start[node];
    int end = row_start[node + 1];         // end-beg even, >= 2

    float l = 0.f;
    float acc[8] = {};

    uint4 r0 = rec[beg + half];
    uint4 r1 = rec[beg + 2 + half];
    uint4 r2 = rec[beg + 4 + half];
    uint4 r3 = rec[beg + 6 + half];

#define GATH(rr) (*(const uint4*)&hh[(size_t)(rr).x * 256 + l32 * 8])
#define PROC(rr, vv)                                                      \
    {                                                                     \
        unsigned u = (head & 2) ? (rr).z : (rr).y;                        \
        unsigned short us = (unsigned short)(u >> wsh);                   \
        float w = __half2float(*(const __half*)&us);                      \
        l += w;                                                           \
        const __half2* hp = (const __half2*)&(vv);                        \
        float2 f0 = __half22float2(hp[0]);                                \
        float2 f1 = __half22float2(hp[1]);                                \
        float2 f2 = __half22float2(hp[2]);                                \
        float2 f3 = __half22float2(hp[3]);                                \
        acc[0] = fmaf(w, f0.x, acc[0]); acc[1] = fmaf(w, f0.y, acc[1]);   \
        acc[2] = fmaf(w, f1.x, acc[2]); acc[3] = fmaf(w, f1.y, acc[3]);   \
        acc[4] = fmaf(w, f2.x, acc[4]); acc[5] = fmaf(w, f2.y, acc[5]);   \
        acc[6] = fmaf(w, f3.x, acc[6]); acc[7] = fmaf(w, f3.y, acc[7]);   \
    }

    uint4 h0 = GATH(r0);
    uint4 h1 = GATH(r1);
    uint4 h2 = GATH(r2);
    uint4 h3;

    int p = beg;
    while (p < end) {
        // phase 0 : pair at p
        h3 = GATH(r3);
        PROC(r0, h0);
        r0 = rec[p + 8 + half];
        p += 2;
        if (p >= end) break;
        // phase 1
        h0 = GATH(r0);
        PROC(r1, h1);
        r1 = rec[p + 8 + half];
        p += 2;
        if (p >= end) break;
        // phase 2
        h1 = GATH(r1);
        PROC(r2, h2);
        r2 = rec[p + 8 + half];
        p += 2;
        if (p >= end) break;
        // phase 3
        h2 = GATH(r2);
        PROC(r3, h3);
        r3 = rec[p + 8 + half];
        p += 2;
    }
#undef GATH
#undef PROC

    // combine the two halves (same node, disjoint edges, same channels)
    l += __shfl_xor(l, 32);
#pragma unroll
    for (int j = 0; j < 8; j++) acc[j] += __shfl_xor(acc[j], 32);

    if (half == 0) {
        float rcp = 1.f / l;
        float4 b0 = *(const float4*)&bias[l32 * 8];
        float4 b1 = *(const float4*)&bias[l32 * 8 + 4];
        float o[8];
        o[0] = fmaf(acc[0], rcp, b0.x); o[1] = fmaf(acc[1], rcp, b0.y);
        o[2] = fmaf(acc[2], rcp, b0.z); o[3] = fmaf(acc[3], rcp, b0.w);
        o[4] = fmaf(acc[4], rcp, b1.x); o[5] = fmaf(acc[5], rcp, b1.y);
        o[6] = fmaf(acc[6], rcp, b1.z); o[7] = fmaf(acc[7], rcp, b1.w);
#pragma unroll
        for (int j = 0; j < 8; j++)
            o[j] = (o[j] > 0.f) ? o[j] : __expf(o[j]) - 1.f;
        if constexpr (OUT_HALF) {
            __half2 q0 = __floats2half2_rn(o[0], o[1]);
            __half2 q1 = __floats2half2_rn(o[2], o[3]);
            __half2 q2 = __floats2half2_rn(o[4], o[5]);
            __half2 q3 = __floats2half2_rn(o[6], o[7]);
            uint4 pk = {*(unsigned*)&q0, *(unsigned*)&q1,
                        *(unsigned*)&q2, *(unsigned*)&q3};
            __half* outh = (__half*)outp;
            *(uint4*)&outh[(size_t)node * 256 + l32 * 8] = pk;
        } else {
            float* outf = (float*)outp;
            *(float4*)&outf[(size_t)node * 256 + l32 * 8] = *(float4*)&o[0];
            *(float4*)&outf[(size_t)node * 256 + l32 * 8 + 4] = *(float4*)&o[4];
        }
    }
}

// ---------------- launch ----------------

extern "C" void kernel_launch(void* const* d_in, const int* in_sizes, int n_in,
                              void* d_out, int out_size, void* d_ws, size_t ws_size,
                              hipStream_t stream) {
    const float* x   = (const float*)d_in[0];
    const int*   ei  = (const int*)d_in[1];
    const float* W1  = (const float*)d_in[2];
    const float* as1 = (const float*)d_in[3];
    const float* ad1 = (const float*)d_in[4];
    const float* b1  = (const float*)d_in[5];
    const float* W2  = (const float*)d_in[6];
    const float* as2 = (const float*)d_in[7];
    const float* ad2 = (const float*)d_in[8];
    const float* b2  = (const float*)d_in[9];
    float* out = (float*)d_out;

    const int N = in_sizes[0] / 128;
    const int E = in_sizes[1] / 2;
    const int Etot = E + N;
    const int EtotMax = (Etot + N + 11) & ~3;  // padded slots + pipeline pad, /4
    const int NB = (N + 1023) / 1024;          // scan blocks (<= 64)

    // workspace layout (16B-aligned segments first)
    __half* h_half = (__half*)d_ws;                        // N*256 fp16
    __half* x1_h   = h_half + (size_t)N * 256;             // N*256 fp16 (x / x1)
    uint4*  rec    = (uint4*)(x1_h + (size_t)N * 256);     // EtotMax x 16B
    __half* a_s_h  = (__half*)(rec + EtotMax);             // N*4 fp16
    float*  a_d    = (float*)(a_s_h + (size_t)N * 4);      // N*4 fp32
    __half* Bt1    = (__half*)(a_d + (size_t)N * 4);       // 256*128 fp16
    __half* Bt2    = Bt1 + 256 * 128;                      // 256*256 fp16
    int*    cnt    = (int*)(Bt2 + 256 * 256);              // N
    int*    fill   = cnt + N;                              // N
    int*    row_st = fill + N;                             // N+2 (pad for align)
    unsigned* edge_pk = (unsigned*)(row_st + (N + 2));     // EtotMax u32
    int*    partials = (int*)(edge_pk + EtotMax);          // NB+1

    hipMemsetAsync(cnt, 0, sizeof(int) * (size_t)N, stream);   // cnt only

    const int xblocks = (N * 32 + 255) / 256;       // x->fp16 blocks
    const int eblocks = (Etot + 255) / 256;         // histogram / scatter blocks
    prep_kernel<<<384 + xblocks + eblocks, 256, 0, stream>>>(
        W1, Bt1, W2, Bt2, x, x1_h, ei, cnt, E, N, xblocks);

    scan_block<<<NB, 1024, 0, stream>>>(cnt, row_st, partials, N);
    scan_add<<<NB, 1024, 0, stream>>>(row_st, partials, cnt, fill, edge_pk,
                                      N, NB, EtotMax);
    scatter_kernel<<<eblocks, 256, 0, stream>>>(ei, fill, edge_pk, E, Etot);

    dim3 ggrid(2 * ((N + 127) / 128));
    int ablocks = (N + 3) / 4;          // 4 nodes (waves) per 256-thread block
    int npairs = EtotMax / 2;
    int fblocks = (npairs + 255) / 256;

    // layer 1 (A = x pre-converted to fp16, living in the x1 buffer)
    gemm_mfma<128><<<ggrid, 256, 0, stream>>>(x1_h, Bt1, h_half,
                                              as1, ad1, a_s_h, a_d, N);
    fill_rec<<<fblocks, 256, 0, stream>>>((const uint2*)edge_pk, a_s_h, a_d,
                                          rec, npairs);
    gat_aggregate<true><<<ablocks, 256, 0, stream>>>(h_half, rec, row_st,
                                                     b1, x1_h, N);
    // layer 2
    gemm_mfma<256><<<ggrid, 256, 0, stream>>>(x1_h, Bt2, h_half,
                                              as2, ad2, a_s_h, a_d, N);
    fill_rec<<<fblocks, 256, 0, stream>>>((const uint2*)edge_pk, a_s_h, a_d,
                                          rec, npairs);
    gat_aggregate<false><<<ablocks, 256, 0, stream>>>(h_half, rec, row_st,
                                                      b2, out, N);
}

// Round 10
// 379.284 us; speedup vs baseline: 1.7716x; 1.7716x over previous
//
#include <hip/hip_runtime.h>
#include <hip/hip_fp16.h>
#include <math.h>

// ---------------------------------------------------------------------------
// GAT encoder, 2 layers.
//   GEMMs: single-term fp16 MFMA (mfma_f32_16x16x32_f16, fp32 accum),
//          single LDS buffer + register prefetch (round-5 structure).
//   CSR: padded to even degree. Edge record is ONE packed u32 (src<<16|dst,
//          N<65536): scatter does a single 4B random store, no random reads
//          (fill seeded = row_start in scan_add). Sentinels (0xFFFFFFFF) are
//          written only into the <=1 hole per odd-degree row; the tail pad
//          slots are filled GRID-DISTRIBUTED in scan_add (every block knows
//          the grand total; round-9's single-thread tail loop cost 293us).
//   fill_rec (2 edges/thread) reads packed edges sequentially, computes
//          w = exp(leaky(a_s[src]+a_d[dst])) per head; rec[i] =
//          {src, w0|w1, w2|w3, 0} (fp16). Sentinel -> zero record.
//   Aggregation: 1 node/wave, 2 edges/iteration (lanes 0-31 edge p, lanes
//          32-63 edge p+1; 16B/lane -> one 1KB gather per pair), depth-4
//          rotation-free software pipeline, prefetch distance 8 edges.
//          Pinned at the L2-miss/Infinity-Cache random-service floor
//          (~3.8 TB/s eff, FETCH ~199MB) - identical counters for 10 rounds.
// ---------------------------------------------------------------------------

#define LEAKY_SLOPE 0.2f

typedef __attribute__((ext_vector_type(8))) short short8v;      // 16B
typedef __attribute__((ext_vector_type(8))) _Float16 half8v;    // 8 fp16
typedef __attribute__((ext_vector_type(4))) float float4v;

// ---------------- fused prep: W->fp16 transposed + x->fp16 + histogram -----

__global__ void prep_kernel(const float* __restrict__ W1, __half* __restrict__ Bt1,
                            const float* __restrict__ W2, __half* __restrict__ Bt2,
                            const float* __restrict__ x, __half* __restrict__ x_h,
                            const int* __restrict__ ei, int* __restrict__ cnt,
                            int E, int N, int xblocks) {
    int b = blockIdx.x;
    if (b < 128) {                       // W1: [128][256] -> Bt1[c*128+k]
        int idx = b * 256 + threadIdx.x;
        int k = idx >> 8, c = idx & 255;
        Bt1[c * 128 + k] = __float2half(W1[idx]);
    } else if (b < 384) {                // W2: [256][256] -> Bt2[c*256+k]
        int idx = (b - 128) * 256 + threadIdx.x;
        int k = idx >> 8, c = idx & 255;
        Bt2[c * 256 + k] = __float2half(W2[idx]);
    } else if (b < 384 + xblocks) {      // x -> fp16, 4 elems/thread
        int t = (b - 384) * 256 + threadIdx.x;
        if (t < N * 32) {
            float4 v = *(const float4*)&x[(size_t)t * 4];
            __half2 h01 = __floats2half2_rn(v.x, v.y);
            __half2 h23 = __floats2half2_rn(v.z, v.w);
            uint2 pk = {*(unsigned*)&h01, *(unsigned*)&h23};
            *(uint2*)&x_h[(size_t)t * 4] = pk;
        }
    } else {                             // degree histogram (incl. self-loops)
        int e = (b - 384 - xblocks) * 256 + threadIdx.x;
        if (e < E + N) {
            int dst = (e < E) ? ei[E + e] : (e - E);
            atomicAdd(&cnt[dst], 1);
        }
    }
}

// ---------------- CSR build (padded to even degree) ----------------

__global__ __launch_bounds__(1024) void scan_block(const int* __restrict__ cnt,
                                                   int* __restrict__ row_start,
                                                   int* __restrict__ partials,
                                                   int n) {
    __shared__ int wsum[16];
    int tid = threadIdx.x, lane = tid & 63, wid = tid >> 6;
    int gi = blockIdx.x * 1024 + tid;
    int v = (gi < n) ? ((cnt[gi] + 1) & ~1) : 0;   // pad degree to even
    int x = v;
#pragma unroll
    for (int off = 1; off < 64; off <<= 1) {
        int y = __shfl_up(x, off, 64);
        if (lane >= off) x += y;
    }
    if (lane == 63) wsum[wid] = x;
    __syncthreads();
    if (wid == 0 && lane < 16) {
        int w = wsum[lane];
#pragma unroll
        for (int off = 1; off < 16; off <<= 1) {
            int y = __shfl_up(w, off, 16);
            if (lane >= off) w += y;
        }
        wsum[lane] = w;
    }
    __syncthreads();
    int excl = x - v + ((wid > 0) ? wsum[wid - 1] : 0);
    if (gi < n) row_start[gi] = excl;
    if (tid == 1023) partials[blockIdx.x] = wsum[15];
}

// scan_add: partials-scan folded in; seeds fill[] = row_start; writes the
// 0xFFFFFFFF sentinel into the <=1 hole of each odd-degree row; tail pad
// slots are sentinel-filled GRID-DISTRIBUTED (every block computes the
// grand total redundantly, so each thread covers a strided slice).
__global__ __launch_bounds__(1024) void scan_add(int* __restrict__ row_start,
                                                 const int* __restrict__ partials,
                                                 const int* __restrict__ cnt,
                                                 int* __restrict__ fill,
                                                 unsigned* __restrict__ edge_pk,
                                                 int n, int nb, int etotmax) {
    __shared__ int spart[2];             // [excl prefix for this block, total]
    if (threadIdx.x < 64) {
        int lane = threadIdx.x;
        int v = (lane < nb) ? partials[lane] : 0;
        int x = v;
#pragma unroll
        for (int off = 1; off < 64; off <<= 1) {
            int y = __shfl_up(x, off, 64);
            if (lane >= off) x += y;
        }
        if (lane == (int)blockIdx.x) spart[0] = x - v;   // exclusive prefix
        if (lane == nb - 1) spart[1] = x;                // grand total
    }
    __syncthreads();
    int gi = blockIdx.x * 1024 + threadIdx.x;
    if (gi < n) {
        int v = row_start[gi] + spart[0];
        row_start[gi] = v;
        fill[gi] = v;                    // scatter cursor starts at row base
        int d = cnt[gi];
        if (d & 1) edge_pk[v + d] = 0xFFFFFFFFu;   // the single hole slot
    }
    if (gi == 0) row_start[n] = spart[1];
    // distributed tail sentinel fill: ~(etotmax-total) slots over the grid
    int total = spart[1];
    int stride = (int)gridDim.x * 1024;
    for (int j = total + gi; j < etotmax; j += stride)
        edge_pk[j] = 0xFFFFFFFFu;
}

__global__ void scatter_kernel(const int* __restrict__ ei,
                               int* __restrict__ fill,
                               unsigned* __restrict__ edge_pk, int E, int Etot) {
    int e = blockIdx.x * blockDim.x + threadIdx.x;
    if (e >= Etot) return;
    int src, dst;
    if (e < E) { src = ei[e]; dst = ei[E + e]; }
    else       { src = e - E; dst = e - E; }
    int pos = atomicAdd(&fill[dst], 1);              // seeded = row_start
    edge_pk[pos] = ((unsigned)src << 16) | (unsigned)dst;  // one 4B store
}

// rec[i] = {src, w0|w1, w2|w3, pad}, w = exp(leaky(a_s+a_d)) fp16.
// Sentinel (0xFFFFFFFF) -> zero record. 2 edges per thread.
__device__ __forceinline__ uint4 make_rec(unsigned pk,
                                          const __half* __restrict__ a_s_h,
                                          const float* __restrict__ a_d) {
    if (pk == 0xFFFFFFFFu) {
        uint4 z = {0u, 0u, 0u, 0u};
        return z;
    }
    unsigned src = pk >> 16, dst = pk & 0xFFFFu;
    uint2 as2 = *(const uint2*)&a_s_h[(size_t)src * 4];
    float4 ad4 = *(const float4*)&a_d[(size_t)dst * 4];
    float2 f01 = __half22float2(*(const __half2*)&as2.x);
    float2 f23 = __half22float2(*(const __half2*)&as2.y);
    float e0 = f01.x + ad4.x, e1 = f01.y + ad4.y;
    float e2 = f23.x + ad4.z, e3 = f23.y + ad4.w;
    e0 = (e0 > 0.f) ? e0 : LEAKY_SLOPE * e0;
    e1 = (e1 > 0.f) ? e1 : LEAKY_SLOPE * e1;
    e2 = (e2 > 0.f) ? e2 : LEAKY_SLOPE * e2;
    e3 = (e3 > 0.f) ? e3 : LEAKY_SLOPE * e3;
    __half2 w01 = __floats2half2_rn(__expf(e0), __expf(e1));
    __half2 w23 = __floats2half2_rn(__expf(e2), __expf(e3));
    uint4 r = {src, *(unsigned*)&w01, *(unsigned*)&w23, 0u};
    return r;
}

__global__ void fill_rec(const uint2* __restrict__ edge_pk2,
                         const __half* __restrict__ a_s_h,
                         const float* __restrict__ a_d,
                         uint4* __restrict__ rec, int npairs) {
    int i = blockIdx.x * blockDim.x + threadIdx.x;
    if (i >= npairs) return;
    uint2 pp = edge_pk2[i];              // {pk0, pk1}
    uint4 r0 = make_rec(pp.x, a_s_h, a_d);
    uint4 r1 = make_rec(pp.y, a_s_h, a_d);
    rec[2 * i] = r0;
    rec[2 * i + 1] = r1;
}

// ---------------- fp16 MFMA GEMM + fused attention dots ---------------
// C[M,256] = A[M,K] @ B[K,256], C stored fp16. A fp16, B fp16 transposed.
// 128x128 tile, BK=32, 2x2 waves, 16 mfma per K-step, register prefetch.

template <int K>
__global__ __launch_bounds__(256) void gemm_mfma(
    const __half* __restrict__ Ah, const __half* __restrict__ Bt,
    __half* __restrict__ Ch,
    const float* __restrict__ att_src, const float* __restrict__ att_dst,
    __half* __restrict__ a_s_out, float* __restrict__ a_d_out, int M) {
    __shared__ short As[128][40];   // [m][k], pad 32->40
    __shared__ short Bs[128][40];   // [n][k] (transposed)

    const int col0 = (blockIdx.x & 1) * 128;
    const int row0 = (blockIdx.x >> 1) * 128;
    const int tid = threadIdx.x;
    const int lane = tid & 63;
    const int wave = tid >> 6;
    const int wr = wave >> 1, wc = wave & 1;
    const int quad = lane >> 4, lc = lane & 15;

    float4v acc[4][4] = {};

    const short* Abits = (const short*)Ah;
    const short* Bbits = (const short*)Bt;

    // staging geometry: thread covers rows (tid>>2) and (tid>>2)+64,
    // k-chunk (tid&3)*8, for both A and B.
    const int sr = tid >> 2;
    const int ko = (tid & 3) * 8;
    const int ga0 = row0 + sr, ga1 = ga0 + 64;
    const size_t gb0 = (size_t)(col0 + sr) * K + ko;
    const size_t gb1 = (size_t)(col0 + sr + 64) * K + ko;

    short8v pa0, pa1, pb0, pb1;
#define LOADT(k0)                                                          \
    {                                                                      \
        pa0 = {}; pa1 = {};                                                \
        if (ga0 < M) pa0 = *(const short8v*)&Abits[(size_t)ga0 * K + (k0) + ko]; \
        if (ga1 < M) pa1 = *(const short8v*)&Abits[(size_t)ga1 * K + (k0) + ko]; \
        pb0 = *(const short8v*)&Bbits[gb0 + (k0)];                         \
        pb1 = *(const short8v*)&Bbits[gb1 + (k0)];                         \
    }

    LOADT(0);

#pragma unroll
    for (int k0 = 0; k0 < K; k0 += 32) {
        *(short8v*)&As[sr][ko] = pa0;
        *(short8v*)&As[sr + 64][ko] = pa1;
        *(short8v*)&Bs[sr][ko] = pb0;
        *(short8v*)&Bs[sr + 64][ko] = pb1;
        __syncthreads();

        if (k0 + 32 < K) LOADT(k0 + 32);   // prefetch under MFMA

        half8v a[4], bv[4];
#pragma unroll
        for (int mt = 0; mt < 4; mt++) {
            int r = wr * 64 + mt * 16 + lc;
            a[mt] = *(const half8v*)&As[r][quad * 8];
        }
#pragma unroll
        for (int nt = 0; nt < 4; nt++) {
            int n = wc * 64 + nt * 16 + lc;
            bv[nt] = *(const half8v*)&Bs[n][quad * 8];
        }
#pragma unroll
        for (int mt = 0; mt < 4; mt++)
#pragma unroll
            for (int nt = 0; nt < 4; nt++)
                acc[mt][nt] = __builtin_amdgcn_mfma_f32_16x16x32_f16(
                    a[mt], bv[nt], acc[mt][nt], 0, 0, 0);
        __syncthreads();
    }
#undef LOADT

    // ---- epilogue: wave's 64 cols = head; C/D: col=lc(+nt*16), row=quad*4+r
    const int head = (col0 >> 6) + wc;
    float as_c[4], ad_c[4];
#pragma unroll
    for (int nt = 0; nt < 4; nt++) {
        as_c[nt] = att_src[head * 64 + nt * 16 + lc];
        ad_c[nt] = att_dst[head * 64 + nt * 16 + lc];
    }

#pragma unroll
    for (int mt = 0; mt < 4; mt++) {
#pragma unroll
        for (int r = 0; r < 4; r++) {
            int gr = row0 + wr * 64 + mt * 16 + quad * 4 + r;
            float ps = 0.f, pd = 0.f;
#pragma unroll
            for (int nt = 0; nt < 4; nt++) {
                float c = acc[mt][nt][r];
                ps = fmaf(c, as_c[nt], ps);
                pd = fmaf(c, ad_c[nt], pd);
                if (gr < M)
                    Ch[(size_t)gr * 256 + col0 + wc * 64 + nt * 16 + lc] =
                        __float2half(c);
            }
#pragma unroll
            for (int off = 1; off < 16; off <<= 1) {
                ps += __shfl_xor(ps, off, 64);
                pd += __shfl_xor(pd, off, 64);
            }
            if (lc == 0 && gr < M) {
                a_s_out[gr * 4 + head] = __float2half(ps);
                a_d_out[gr * 4 + head] = pd;
            }
        }
    }
}

// ---------------- fused aggregate + bias + elu ----------------
// 1 node/wave, 2 edges/iteration, padded-even rows: no clamps, no tail
// checks. Depth-4 rotation-free pipeline, prefetch distance 8 edges.

template <bool OUT_HALF>
__global__ __launch_bounds__(256) void gat_aggregate(
    const __half* __restrict__ hh, const uint4* __restrict__ rec,
    const int* __restrict__ row_start, const float* __restrict__ bias,
    void* __restrict__ outp, int n) {
    int node = (blockIdx.x * blockDim.x + threadIdx.x) >> 6;
    if (node >= n) return;                 // wave-uniform
    int lane = threadIdx.x & 63;
    int half = lane >> 5, l32 = lane & 31;
    int head = l32 >> 3;
    unsigned wsh = (head & 1) << 4;        // 16-bit select shift, hoisted

    int beg = row_start[node];
    int end = row_start[node + 1];         // end-beg even, >= 2

    float l = 0.f;
    float acc[8] = {};

    uint4 r0 = rec[beg + half];
    uint4 r1 = rec[beg + 2 + half];
    uint4 r2 = rec[beg + 4 + half];
    uint4 r3 = rec[beg + 6 + half];

#define GATH(rr) (*(const uint4*)&hh[(size_t)(rr).x * 256 + l32 * 8])
#define PROC(rr, vv)                                                      \
    {                                                                     \
        unsigned u = (head & 2) ? (rr).z : (rr).y;                        \
        unsigned short us = (unsigned short)(u >> wsh);                   \
        float w = __half2float(*(const __half*)&us);                      \
        l += w;                                                           \
        const __half2* hp = (const __half2*)&(vv);                        \
        float2 f0 = __half22float2(hp[0]);                                \
        float2 f1 = __half22float2(hp[1]);                                \
        float2 f2 = __half22float2(hp[2]);                                \
        float2 f3 = __half22float2(hp[3]);                                \
        acc[0] = fmaf(w, f0.x, acc[0]); acc[1] = fmaf(w, f0.y, acc[1]);   \
        acc[2] = fmaf(w, f1.x, acc[2]); acc[3] = fmaf(w, f1.y, acc[3]);   \
        acc[4] = fmaf(w, f2.x, acc[4]); acc[5] = fmaf(w, f2.y, acc[5]);   \
        acc[6] = fmaf(w, f3.x, acc[6]); acc[7] = fmaf(w, f3.y, acc[7]);   \
    }

    uint4 h0 = GATH(r0);
    uint4 h1 = GATH(r1);
    uint4 h2 = GATH(r2);
    uint4 h3;

    int p = beg;
    while (p < end) {
        // phase 0 : pair at p
        h3 = GATH(r3);
        PROC(r0, h0);
        r0 = rec[p + 8 + half];
        p += 2;
        if (p >= end) break;
        // phase 1
        h0 = GATH(r0);
        PROC(r1, h1);
        r1 = rec[p + 8 + half];
        p += 2;
        if (p >= end) break;
        // phase 2
        h1 = GATH(r1);
        PROC(r2, h2);
        r2 = rec[p + 8 + half];
        p += 2;
        if (p >= end) break;
        // phase 3
        h2 = GATH(r2);
        PROC(r3, h3);
        r3 = rec[p + 8 + half];
        p += 2;
    }
#undef GATH
#undef PROC

    // combine the two halves (same node, disjoint edges, same channels)
    l += __shfl_xor(l, 32);
#pragma unroll
    for (int j = 0; j < 8; j++) acc[j] += __shfl_xor(acc[j], 32);

    if (half == 0) {
        float rcp = 1.f / l;
        float4 b0 = *(const float4*)&bias[l32 * 8];
        float4 b1 = *(const float4*)&bias[l32 * 8 + 4];
        float o[8];
        o[0] = fmaf(acc[0], rcp, b0.x); o[1] = fmaf(acc[1], rcp, b0.y);
        o[2] = fmaf(acc[2], rcp, b0.z); o[3] = fmaf(acc[3], rcp, b0.w);
        o[4] = fmaf(acc[4], rcp, b1.x); o[5] = fmaf(acc[5], rcp, b1.y);
        o[6] = fmaf(acc[6], rcp, b1.z); o[7] = fmaf(acc[7], rcp, b1.w);
#pragma unroll
        for (int j = 0; j < 8; j++)
            o[j] = (o[j] > 0.f) ? o[j] : __expf(o[j]) - 1.f;
        if constexpr (OUT_HALF) {
            __half2 q0 = __floats2half2_rn(o[0], o[1]);
            __half2 q1 = __floats2half2_rn(o[2], o[3]);
            __half2 q2 = __floats2half2_rn(o[4], o[5]);
            __half2 q3 = __floats2half2_rn(o[6], o[7]);
            uint4 pk = {*(unsigned*)&q0, *(unsigned*)&q1,
                        *(unsigned*)&q2, *(unsigned*)&q3};
            __half* outh = (__half*)outp;
            *(uint4*)&outh[(size_t)node * 256 + l32 * 8] = pk;
        } else {
            float* outf = (float*)outp;
            *(float4*)&outf[(size_t)node * 256 + l32 * 8] = *(float4*)&o[0];
            *(float4*)&outf[(size_t)node * 256 + l32 * 8 + 4] = *(float4*)&o[4];
        }
    }
}

// ---------------- launch ----------------

extern "C" void kernel_launch(void* const* d_in, const int* in_sizes, int n_in,
                              void* d_out, int out_size, void* d_ws, size_t ws_size,
                              hipStream_t stream) {
    const float* x   = (const float*)d_in[0];
    const int*   ei  = (const int*)d_in[1];
    const float* W1  = (const float*)d_in[2];
    const float* as1 = (const float*)d_in[3];
    const float* ad1 = (const float*)d_in[4];
    const float* b1  = (const float*)d_in[5];
    const float* W2  = (const float*)d_in[6];
    const float* as2 = (const float*)d_in[7];
    const float* ad2 = (const float*)d_in[8];
    const float* b2  = (const float*)d_in[9];
    float* out = (float*)d_out;

    const int N = in_sizes[0] / 128;
    const int E = in_sizes[1] / 2;
    const int Etot = E + N;
    const int EtotMax = (Etot + N + 11) & ~3;  // padded slots + pipeline pad, /4
    const int NB = (N + 1023) / 1024;          // scan blocks (<= 64)

    // workspace layout (16B-aligned segments first)
    __half* h_half = (__half*)d_ws;                        // N*256 fp16
    __half* x1_h   = h_half + (size_t)N * 256;             // N*256 fp16 (x / x1)
    uint4*  rec    = (uint4*)(x1_h + (size_t)N * 256);     // EtotMax x 16B
    __half* a_s_h  = (__half*)(rec + EtotMax);             // N*4 fp16
    float*  a_d    = (float*)(a_s_h + (size_t)N * 4);      // N*4 fp32
    __half* Bt1    = (__half*)(a_d + (size_t)N * 4);       // 256*128 fp16
    __half* Bt2    = Bt1 + 256 * 128;                      // 256*256 fp16
    int*    cnt    = (int*)(Bt2 + 256 * 256);              // N
    int*    fill   = cnt + N;                              // N
    int*    row_st = fill + N;                             // N+2 (pad for align)
    unsigned* edge_pk = (unsigned*)(row_st + (N + 2));     // EtotMax u32
    int*    partials = (int*)(edge_pk + EtotMax);          // NB+1

    hipMemsetAsync(cnt, 0, sizeof(int) * (size_t)N, stream);   // cnt only

    const int xblocks = (N * 32 + 255) / 256;       // x->fp16 blocks
    const int eblocks = (Etot + 255) / 256;         // histogram / scatter blocks
    prep_kernel<<<384 + xblocks + eblocks, 256, 0, stream>>>(
        W1, Bt1, W2, Bt2, x, x1_h, ei, cnt, E, N, xblocks);

    scan_block<<<NB, 1024, 0, stream>>>(cnt, row_st, partials, N);
    scan_add<<<NB, 1024, 0, stream>>>(row_st, partials, cnt, fill, edge_pk,
                                      N, NB, EtotMax);
    scatter_kernel<<<eblocks, 256, 0, stream>>>(ei, fill, edge_pk, E, Etot);

    dim3 ggrid(2 * ((N + 127) / 128));
    int ablocks = (N + 3) / 4;          // 4 nodes (waves) per 256-thread block
    int npairs = EtotMax / 2;
    int fblocks = (npairs + 255) / 256;

    // layer 1 (A = x pre-converted to fp16, living in the x1 buffer)
    gemm_mfma<128><<<ggrid, 256, 0, stream>>>(x1_h, Bt1, h_half,
                                              as1, ad1, a_s_h, a_d, N);
    fill_rec<<<fblocks, 256, 0, stream>>>((const uint2*)edge_pk, a_s_h, a_d,
                                          rec, npairs);
    gat_aggregate<true><<<ablocks, 256, 0, stream>>>(h_half, rec, row_st,
                                                     b1, x1_h, N);
    // layer 2
    gemm_mfma<256><<<ggrid, 256, 0, stream>>>(x1_h, Bt2, h_half,
                                              as2, ad2, a_s_h, a_d, N);
    fill_rec<<<fblocks, 256, 0, stream>>>((const uint2*)edge_pk, a_s_h, a_d,
                                          rec, npairs);
    gat_aggregate<false><<<ablocks, 256, 0, stream>>>(h_half, rec, row_st,
                                                      b2, out, N);
}